// Round 6
// baseline (370.396 us; speedup 1.0000x reference)
//
#include <hip/hip_runtime.h>
#include <hip/hip_bf16.h>

// GraphSAGE fused kernels for MI355X (gfx950).
// N=768, NODE_IN=64, EDGE_IN=32, H=128, ROUNDS=2.
//
// Round 6: round 5 structure (pruned, barrier-free, spill-free) + the
// 3-waves/SIMD occupancy fix: VGPR 172 is 2 regs over the 512/3=170 cliff.
// bereg[8] -> be_lds (broadcast LDS reads are free), __launch_bounds__(256,3)
// pins the allocator at 170. LDS 51.7KB -> 3 blocks/CU fit (163840/3=54613).

typedef __bf16 bf16x8 __attribute__((ext_vector_type(8)));
typedef float f32x4 __attribute__((ext_vector_type(4)));

#define NN 768

static __device__ __forceinline__ unsigned short to_bf16u(float x) {
    return __builtin_bit_cast(unsigned short, (__bf16)x);
}

// ---------------------------------------------------------------- fused prep
// blocks 0..575   : adj transpose (32x32 tiles)
// blocks 576..655 : weight transposes We->WeT, Wa[H:]->Wa2T (bf16 k-minor)
// blocks 656..1039: h0 = relu(nf@Wn+bn) and sp = h0@Wa[:H]+ba (plain layout)
__global__ __launch_bounds__(256) void k_prep(
                       const float* __restrict__ adj, float* __restrict__ adjT,
                       const float* __restrict__ We, const float* __restrict__ Wa,
                       unsigned short* __restrict__ WeT, unsigned short* __restrict__ Wa2T,
                       const float* __restrict__ nf, const float* __restrict__ Wn,
                       const float* __restrict__ bn, const float* __restrict__ ba,
                       float* __restrict__ h, float* __restrict__ sp) {
    const int b = blockIdx.x, tid = threadIdx.x;
    if (b < 576) {
        __shared__ float tile[32][33];
        int bx = b % 24, by = b / 24;
        int tx = tid & 31, ty = tid >> 5;  // 32 x 8
#pragma unroll
        for (int yy = 0; yy < 32; yy += 8)
            tile[ty + yy][tx] = adj[(size_t)(by * 32 + ty + yy) * NN + bx * 32 + tx];
        __syncthreads();
#pragma unroll
        for (int yy = 0; yy < 32; yy += 8)
            adjT[(size_t)(bx * 32 + ty + yy) * NN + by * 32 + tx] = tile[tx][ty + yy];
    } else if (b < 656) {
        int g = (b - 576) * 256 + tid;
        if (g < 128 * 32) {
            int c = g >> 5, f = g & 31;
            WeT[g] = to_bf16u(We[f * 128 + c]);
        } else {
            int g2 = g - 128 * 32;
            int c = g2 >> 7, k = g2 & 127;
            Wa2T[g2] = to_bf16u(Wa[(128 + k) * 128 + c]);
        }
    } else {
        __shared__ float nf_l[2][64];
        __shared__ float h_l[2][128];
        int row = tid >> 7, t = tid & 127;
        int i = (b - 656) * 2 + row;
        if (t < 64) nf_l[row][t] = nf[i * 64 + t];
        __syncthreads();
        float acc = bn[t];
#pragma unroll 8
        for (int f = 0; f < 64; ++f) acc += nf_l[row][f] * Wn[f * 128 + t];
        acc = fmaxf(acc, 0.f);
        h[i * 128 + t] = acc;
        h_l[row][t] = acc;
        __syncthreads();
        float spv = ba[t];
#pragma unroll 8
        for (int f = 0; f < 128; ++f) spv += h_l[row][f] * Wa[f * 128 + t];
        sp[i * 128 + t] = spv;
    }
}

// ---------------------------------------------------------------- the big fused kernel
// Block = receiver j, 4 waves. Wave-0 compacts senders with adj[i,j]=1 into
// idx_lds; each wave then owns 16-row gathered chunks end-to-end.
__global__ __launch_bounds__(256, 3) void k_big(
    const float* __restrict__ ef, const float* __restrict__ adjT,
    const float* __restrict__ sp, const unsigned short* __restrict__ WeT,
    const unsigned short* __restrict__ Wa2T, const float* __restrict__ be,
    float* __restrict__ agg) {
    __shared__ unsigned short wa2_lds[128 * 128];              // 32KB, XOR-swizzled
    __shared__ __align__(16) unsigned short e_lds[4][16 * 128]; // 4KB per wave
    __shared__ unsigned short idx_lds[NN];                      // compacted senders
    __shared__ float be_lds[128];
    __shared__ int s_cnt;
    __shared__ float s_invdeg;

    const int tid  = threadIdx.x;
    const int j    = blockIdx.x;
    const int lane = tid & 63;
    const int wv   = tid >> 6;
    const int lg   = lane >> 4;
    const int lr   = lane & 15;

    // ---- stage Wa2T -> swizzled LDS
    {
        const int col = tid >> 1;
        const int kb  = (tid & 1) * 64;
#pragma unroll
        for (int m = 0; m < 8; ++m) {
            bf16x8 v = *reinterpret_cast<const bf16x8*>(Wa2T + col * 128 + kb + 8 * m);
            int idx = (col * 128 + kb + 8 * m) ^ ((col & 7) << 3);
            *reinterpret_cast<bf16x8*>(&wa2_lds[idx]) = v;
        }
    }
    if (tid < 128) be_lds[tid] = be[tid];
    // ---- GEMM1 B-frags (We) in regs
    bf16x8 bwe[8];
#pragma unroll
    for (int t = 0; t < 8; ++t) {
        int col = 16 * t + lr;
        bwe[t] = *reinterpret_cast<const bf16x8*>(WeT + col * 32 + 8 * lg);
    }
    // ---- wave 0: ballot-compaction of adj column j
    if (wv == 0) {
        int cnt = 0;
#pragma unroll
        for (int b = 0; b < 12; ++b) {
            float v = adjT[(size_t)j * NN + b * 64 + lane];
            unsigned long long m = __ballot(v != 0.0f);
            if (v != 0.0f) {
                int pos = cnt + __popcll(m & ((1ULL << lane) - 1ULL));
                idx_lds[pos] = (unsigned short)(b * 64 + lane);
            }
            cnt += (int)__popcll(m);
        }
        if (lane == 0) {
            s_cnt = cnt;
            s_invdeg = 1.0f / fmaxf((float)cnt, 1.0f);
        }
    }
    __syncthreads();

    const int cnt = s_cnt;
    const int K = (cnt + 63) >> 6;   // super-chunks of 64 slots (16 per wave)

    float aggp[8] = {0.f, 0.f, 0.f, 0.f, 0.f, 0.f, 0.f, 0.f};

    // prefetch chunk 0 row for this lane (slot = 16wv + lr)
    float4 a0, a1;
    if (K > 0) {
        int s0 = 16 * wv + lr;
        int r0 = (s0 < cnt) ? (int)idx_lds[s0] : 0;
        const float* p = ef + ((size_t)r0 * NN + j) * 32 + 8 * lg;
        a0 = *reinterpret_cast<const float4*>(p);
        a1 = *reinterpret_cast<const float4*>(p + 4);
    }

    for (int n = 0; n < K; ++n) {
        const int sb = 64 * n + 16 * wv;    // this wave's slot base

        bf16x8 a;
        a[0] = (__bf16)a0.x; a[1] = (__bf16)a0.y; a[2] = (__bf16)a0.z; a[3] = (__bf16)a0.w;
        a[4] = (__bf16)a1.x; a[5] = (__bf16)a1.y; a[6] = (__bf16)a1.z; a[7] = (__bf16)a1.w;

        // prefetch next chunk's ef row
        float4 nx0, nx1;
        if (n + 1 < K) {
            int sn = sb + 64 + lr;
            int rn = (sn < cnt) ? (int)idx_lds[sn] : 0;
            const float* p = ef + ((size_t)rn * NN + j) * 32 + 8 * lg;
            nx0 = *reinterpret_cast<const float4*>(p);
            nx1 = *reinterpret_cast<const float4*>(p + 4);
        }

        // ---- GEMM1: E(16x128) = relu(EF @ We + be), write swizzled E
#pragma unroll
        for (int t = 0; t < 8; ++t) {
            float bb = be_lds[16 * t + lr];
            f32x4 c;
            c[0] = bb; c[1] = bb; c[2] = bb; c[3] = bb;
            f32x4 C1 = __builtin_amdgcn_mfma_f32_16x16x32_bf16(a, bwe[t], c, 0, 0, 0);
#pragma unroll
            for (int r = 0; r < 4; ++r) {
                int row = 4 * lg + r, col = 16 * t + lr;
                int idx = (row * 128 + col) ^ ((row & 7) << 3);
                e_lds[wv][idx] = to_bf16u(fmaxf(C1[r], 0.f));
            }
        }
        // ---- GEMM2 A-frags from private E
        bf16x8 ae[4];
#pragma unroll
        for (int s = 0; s < 4; ++s) {
            int idx = (lr * 128 + 32 * s + 8 * lg) ^ ((lr & 7) << 3);
            ae[s] = *reinterpret_cast<const bf16x8*>(&e_lds[wv][idx]);
        }
        // C/D row slots for this lane
        int srow[4];
        float w[4];
#pragma unroll
        for (int r = 0; r < 4; ++r) {
            int s = sb + 4 * lg + r;
            bool valid = s < cnt;
            srow[r] = valid ? (int)idx_lds[s] : 0;
            w[r] = valid ? 1.0f : 0.0f;
        }
        // ---- GEMM2: P = E @ Wa2 + sp(gathered), relu, accumulate
#pragma unroll
        for (int t = 0; t < 8; ++t) {
            const int col = 16 * t + lr;
            f32x4 acc;
#pragma unroll
            for (int r = 0; r < 4; ++r)
                acc[r] = sp[(size_t)srow[r] * 128 + col];
#pragma unroll
            for (int s = 0; s < 4; ++s) {
                int widx = (col * 128 + 32 * s + 8 * lg) ^ ((col & 7) << 3);
                bf16x8 bw = *reinterpret_cast<const bf16x8*>(&wa2_lds[widx]);
                acc = __builtin_amdgcn_mfma_f32_16x16x32_bf16(ae[s], bw, acc, 0, 0, 0);
            }
#pragma unroll
            for (int r = 0; r < 4; ++r)
                aggp[t] += fmaxf(acc[r], 0.f) * w[r];
        }

        if (n + 1 < K) { a0 = nx0; a1 = nx1; }
    }

    // ---- reduce: sum over lg groups within wave, then across waves
    float* redw = reinterpret_cast<float*>(&e_lds[wv][0]);
    __syncthreads();   // ensure all E reads done before reuse as reduce buffer
#pragma unroll
    for (int t = 0; t < 8; ++t) {
        float v = aggp[t];
        v += __shfl_xor(v, 16);
        v += __shfl_xor(v, 32);
        if (lane < 16) redw[16 * t + lane] = v;
    }
    __syncthreads();
    if (tid < 128) {
        const float* r0 = reinterpret_cast<const float*>(&e_lds[0][0]);
        const float* r1 = reinterpret_cast<const float*>(&e_lds[1][0]);
        const float* r2 = reinterpret_cast<const float*>(&e_lds[2][0]);
        const float* r3 = reinterpret_cast<const float*>(&e_lds[3][0]);
        agg[(size_t)j * 128 + tid] = (r0[tid] + r1[tid] + r2[tid] + r3[tid]) * s_invdeg;
    }
}

// ---------------------------------------------------------------- update (+ next-round sp, or final out)
template <int LAST>
__global__ __launch_bounds__(256) void k_upd(
                      const float* __restrict__ h_in, const float* __restrict__ agg,
                      const float* __restrict__ Wu, const float* __restrict__ bu,
                      const float* __restrict__ Wa, const float* __restrict__ ba,
                      float* __restrict__ h_out, float* __restrict__ sp,
                      float* __restrict__ out) {
    __shared__ float buf[2][256];
    __shared__ float hn[2][128];
    const int tid = threadIdx.x;
    const int row = tid >> 7, t = tid & 127;
    const int i = blockIdx.x * 2 + row;
    buf[row][t] = h_in[i * 128 + t];
    buf[row][128 + t] = agg[i * 128 + t];
    __syncthreads();
    float acc = bu[t];
#pragma unroll 8
    for (int f = 0; f < 256; ++f) acc += buf[row][f] * Wu[f * 128 + t];
    acc = fmaxf(acc, 0.f);
    if (LAST) {
        out[i * 128 + t] = acc;
    } else {
        h_out[i * 128 + t] = acc;
        hn[row][t] = acc;
        __syncthreads();
        float spv = ba[t];
#pragma unroll 8
        for (int f = 0; f < 128; ++f) spv += hn[row][f] * Wa[f * 128 + t];
        sp[i * 128 + t] = spv;
    }
}

// ---------------------------------------------------------------- graph embedding (reads h from out)
__global__ __launch_bounds__(64) void k_gemb(const float* __restrict__ out_h, float* __restrict__ out) {
    int c = blockIdx.x, l = threadIdx.x;
    float acc = 0.f;
    for (int i = l; i < NN; i += 64) acc += out_h[(size_t)i * 128 + c];
#pragma unroll
    for (int off = 32; off; off >>= 1) acc += __shfl_down(acc, off);
    if (l == 0) out[NN * 128 + c] = acc * (1.0f / 768.0f);
}

extern "C" void kernel_launch(void* const* d_in, const int* in_sizes, int n_in,
                              void* d_out, int out_size, void* d_ws, size_t ws_size,
                              hipStream_t stream) {
    const float* nf  = (const float*)d_in[0];
    const float* ef  = (const float*)d_in[1];
    const float* adj = (const float*)d_in[2];
    const float* Wn  = (const float*)d_in[3];
    const float* bn  = (const float*)d_in[4];
    const float* We  = (const float*)d_in[5];
    const float* be  = (const float*)d_in[6];
    const float* Wa  = (const float*)d_in[7];
    const float* ba  = (const float*)d_in[8];
    const float* Wu  = (const float*)d_in[9];
    const float* bu  = (const float*)d_in[10];
    float* out = (float*)d_out;

    // workspace carve-up (floats): h | agg | sp | adjT | WeT(bf16) | Wa2T(bf16)
    float* h_buf = (float*)d_ws;
    float* agg   = h_buf + NN * 128;
    float* sp    = agg + NN * 128;
    float* adjT  = sp + NN * 128;
    unsigned short* WeT  = (unsigned short*)(adjT + NN * NN);
    unsigned short* Wa2T = WeT + 128 * 32;

    k_prep<<<1040, 256, 0, stream>>>(adj, adjT, We, Wa, WeT, Wa2T, nf, Wn, bn, ba, h_buf, sp);

    k_big<<<NN, 256, 0, stream>>>(ef, adjT, sp, WeT, Wa2T, be, agg);
    k_upd<0><<<NN / 2, 256, 0, stream>>>(h_buf, agg, Wu, bu, Wa, ba, h_buf, sp, out);
    k_big<<<NN, 256, 0, stream>>>(ef, adjT, sp, WeT, Wa2T, be, agg);
    k_upd<1><<<NN / 2, 256, 0, stream>>>(h_buf, agg, Wu, bu, Wa, ba, h_buf, sp, out);

    k_gemb<<<128, 64, 0, stream>>>(out, out);
}

// Round 7
// 164.086 us; speedup vs baseline: 2.2573x; 2.2573x over previous
//
#include <hip/hip_runtime.h>
#include <hip/hip_bf16.h>

// GraphSAGE fused kernels for MI355X (gfx950).
// N=768, NODE_IN=64, EDGE_IN=32, H=128, ROUNDS=2.
//
// Round 7: round 5 structure (the only spill-free config: plain
// __launch_bounds__(256); the min-waves arg is toxic — R2/R3/R4/R6 all
// spilled) + sp C-init register prefetch: the 32 scattered 4B sp loads per
// chunk were consumed t-by-t right before GEMM2 (8 serial ~600cyc rounds);
// now the whole next-chunk sp tile is prefetched into f32x4 spv_next[8]
// during the current chunk's MFMA work. VGPRs 172->~230 are free (occupancy
// band (128,256] is flat per m69 quantum).

typedef __bf16 bf16x8 __attribute__((ext_vector_type(8)));
typedef float f32x4 __attribute__((ext_vector_type(4)));

#define NN 768

static __device__ __forceinline__ unsigned short to_bf16u(float x) {
    return __builtin_bit_cast(unsigned short, (__bf16)x);
}

// ---------------------------------------------------------------- fused prep
// blocks 0..575   : adj transpose (32x32 tiles)
// blocks 576..655 : weight transposes We->WeT, Wa[H:]->Wa2T (bf16 k-minor)
// blocks 656..1039: h0 = relu(nf@Wn+bn) and sp = h0@Wa[:H]+ba (plain layout)
__global__ __launch_bounds__(256) void k_prep(
                       const float* __restrict__ adj, float* __restrict__ adjT,
                       const float* __restrict__ We, const float* __restrict__ Wa,
                       unsigned short* __restrict__ WeT, unsigned short* __restrict__ Wa2T,
                       const float* __restrict__ nf, const float* __restrict__ Wn,
                       const float* __restrict__ bn, const float* __restrict__ ba,
                       float* __restrict__ h, float* __restrict__ sp) {
    const int b = blockIdx.x, tid = threadIdx.x;
    if (b < 576) {
        __shared__ float tile[32][33];
        int bx = b % 24, by = b / 24;
        int tx = tid & 31, ty = tid >> 5;  // 32 x 8
#pragma unroll
        for (int yy = 0; yy < 32; yy += 8)
            tile[ty + yy][tx] = adj[(size_t)(by * 32 + ty + yy) * NN + bx * 32 + tx];
        __syncthreads();
#pragma unroll
        for (int yy = 0; yy < 32; yy += 8)
            adjT[(size_t)(bx * 32 + ty + yy) * NN + by * 32 + tx] = tile[tx][ty + yy];
    } else if (b < 656) {
        int g = (b - 576) * 256 + tid;
        if (g < 128 * 32) {
            int c = g >> 5, f = g & 31;
            WeT[g] = to_bf16u(We[f * 128 + c]);
        } else {
            int g2 = g - 128 * 32;
            int c = g2 >> 7, k = g2 & 127;
            Wa2T[g2] = to_bf16u(Wa[(128 + k) * 128 + c]);
        }
    } else {
        __shared__ float nf_l[2][64];
        __shared__ float h_l[2][128];
        int row = tid >> 7, t = tid & 127;
        int i = (b - 656) * 2 + row;
        if (t < 64) nf_l[row][t] = nf[i * 64 + t];
        __syncthreads();
        float acc = bn[t];
#pragma unroll 8
        for (int f = 0; f < 64; ++f) acc += nf_l[row][f] * Wn[f * 128 + t];
        acc = fmaxf(acc, 0.f);
        h[i * 128 + t] = acc;
        h_l[row][t] = acc;
        __syncthreads();
        float spv = ba[t];
#pragma unroll 8
        for (int f = 0; f < 128; ++f) spv += h_l[row][f] * Wa[f * 128 + t];
        sp[i * 128 + t] = spv;
    }
}

// ---------------------------------------------------------------- the big fused kernel
// Block = receiver j, 4 waves. Wave-0 compacts senders with adj[i,j]=1 into
// idx_lds; each wave then owns 16-row gathered chunks end-to-end.
__global__ __launch_bounds__(256) void k_big(
    const float* __restrict__ ef, const float* __restrict__ adjT,
    const float* __restrict__ sp, const unsigned short* __restrict__ WeT,
    const unsigned short* __restrict__ Wa2T, const float* __restrict__ be,
    float* __restrict__ agg) {
    __shared__ unsigned short wa2_lds[128 * 128];               // 32KB, XOR-swizzled
    __shared__ __align__(16) unsigned short e_lds[4][16 * 128]; // 4KB per wave
    __shared__ unsigned short idx_lds[NN];                      // compacted senders
    __shared__ float be_lds[128];
    __shared__ int s_cnt;
    __shared__ float s_invdeg;

    const int tid  = threadIdx.x;
    const int j    = blockIdx.x;
    const int lane = tid & 63;
    const int wv   = tid >> 6;
    const int lg   = lane >> 4;
    const int lr   = lane & 15;

    // ---- stage Wa2T -> swizzled LDS
    {
        const int col = tid >> 1;
        const int kb  = (tid & 1) * 64;
#pragma unroll
        for (int m = 0; m < 8; ++m) {
            bf16x8 v = *reinterpret_cast<const bf16x8*>(Wa2T + col * 128 + kb + 8 * m);
            int idx = (col * 128 + kb + 8 * m) ^ ((col & 7) << 3);
            *reinterpret_cast<bf16x8*>(&wa2_lds[idx]) = v;
        }
    }
    if (tid < 128) be_lds[tid] = be[tid];
    // ---- GEMM1 B-frags (We) in regs
    bf16x8 bwe[8];
#pragma unroll
    for (int t = 0; t < 8; ++t) {
        int col = 16 * t + lr;
        bwe[t] = *reinterpret_cast<const bf16x8*>(WeT + col * 32 + 8 * lg);
    }
    // ---- wave 0: ballot-compaction of adj column j
    if (wv == 0) {
        int cnt = 0;
#pragma unroll
        for (int b = 0; b < 12; ++b) {
            float v = adjT[(size_t)j * NN + b * 64 + lane];
            unsigned long long m = __ballot(v != 0.0f);
            if (v != 0.0f) {
                int pos = cnt + __popcll(m & ((1ULL << lane) - 1ULL));
                idx_lds[pos] = (unsigned short)(b * 64 + lane);
            }
            cnt += (int)__popcll(m);
        }
        if (lane == 0) {
            s_cnt = cnt;
            s_invdeg = 1.0f / fmaxf((float)cnt, 1.0f);
        }
    }
    __syncthreads();

    const int cnt = s_cnt;
    const int K = (cnt + 63) >> 6;   // super-chunks of 64 slots (16 per wave)

    float aggp[8] = {0.f, 0.f, 0.f, 0.f, 0.f, 0.f, 0.f, 0.f};

    // ---- prefetch chunk 0: ef row + full sp C-init tile + validity
    float4 a0, a1;
    f32x4 spv_c[8];
    float w_c[4];
    if (K > 0) {
        int s0 = 16 * wv + lr;
        int r0 = (s0 < cnt) ? (int)idx_lds[s0] : 0;
        const float* p = ef + ((size_t)r0 * NN + j) * 32 + 8 * lg;
        a0 = *reinterpret_cast<const float4*>(p);
        a1 = *reinterpret_cast<const float4*>(p + 4);
#pragma unroll
        for (int r = 0; r < 4; ++r) {
            int s = 16 * wv + 4 * lg + r;
            bool valid = s < cnt;
            int row = valid ? (int)idx_lds[s] : 0;
            w_c[r] = valid ? 1.0f : 0.0f;
            const float* pr = sp + (size_t)row * 128 + lr;
#pragma unroll
            for (int t = 0; t < 8; ++t) spv_c[t][r] = pr[16 * t];
        }
    }

    for (int n = 0; n < K; ++n) {
        const int sb = 64 * n + 16 * wv;    // this wave's slot base

        bf16x8 a;
        a[0] = (__bf16)a0.x; a[1] = (__bf16)a0.y; a[2] = (__bf16)a0.z; a[3] = (__bf16)a0.w;
        a[4] = (__bf16)a1.x; a[5] = (__bf16)a1.y; a[6] = (__bf16)a1.z; a[7] = (__bf16)a1.w;

        // ---- issue next chunk's prefetches (ef row + sp tile) early
        float4 nx0, nx1;
        f32x4 spv_n[8];
        float w_n[4];
        if (n + 1 < K) {
            int sn = sb + 64 + lr;
            int rn = (sn < cnt) ? (int)idx_lds[sn] : 0;
            const float* p = ef + ((size_t)rn * NN + j) * 32 + 8 * lg;
            nx0 = *reinterpret_cast<const float4*>(p);
            nx1 = *reinterpret_cast<const float4*>(p + 4);
#pragma unroll
            for (int r = 0; r < 4; ++r) {
                int s = sb + 64 + 4 * lg + r;
                bool valid = s < cnt;
                int row = valid ? (int)idx_lds[s] : 0;
                w_n[r] = valid ? 1.0f : 0.0f;
                const float* pr = sp + (size_t)row * 128 + lr;
#pragma unroll
                for (int t = 0; t < 8; ++t) spv_n[t][r] = pr[16 * t];
            }
        }

        // ---- GEMM1: E(16x128) = relu(EF @ We + be), write swizzled E
#pragma unroll
        for (int t = 0; t < 8; ++t) {
            float bb = be_lds[16 * t + lr];
            f32x4 c;
            c[0] = bb; c[1] = bb; c[2] = bb; c[3] = bb;
            f32x4 C1 = __builtin_amdgcn_mfma_f32_16x16x32_bf16(a, bwe[t], c, 0, 0, 0);
#pragma unroll
            for (int r = 0; r < 4; ++r) {
                int row = 4 * lg + r, col = 16 * t + lr;
                int idx = (row * 128 + col) ^ ((row & 7) << 3);
                e_lds[wv][idx] = to_bf16u(fmaxf(C1[r], 0.f));
            }
        }
        // ---- GEMM2 A-frags from private E (wave-synchronous round trip)
        bf16x8 ae[4];
#pragma unroll
        for (int s = 0; s < 4; ++s) {
            int idx = (lr * 128 + 32 * s + 8 * lg) ^ ((lr & 7) << 3);
            ae[s] = *reinterpret_cast<const bf16x8*>(&e_lds[wv][idx]);
        }
        // ---- GEMM2: P = E @ Wa2 + sp(prefetched), relu, accumulate
#pragma unroll
        for (int t = 0; t < 8; ++t) {
            const int col = 16 * t + lr;
            f32x4 acc = spv_c[t];
#pragma unroll
            for (int s = 0; s < 4; ++s) {
                int widx = (col * 128 + 32 * s + 8 * lg) ^ ((col & 7) << 3);
                bf16x8 bw = *reinterpret_cast<const bf16x8*>(&wa2_lds[widx]);
                acc = __builtin_amdgcn_mfma_f32_16x16x32_bf16(ae[s], bw, acc, 0, 0, 0);
            }
#pragma unroll
            for (int r = 0; r < 4; ++r)
                aggp[t] += fmaxf(acc[r], 0.f) * w_c[r];
        }

        if (n + 1 < K) {
            a0 = nx0; a1 = nx1;
#pragma unroll
            for (int t = 0; t < 8; ++t) spv_c[t] = spv_n[t];
#pragma unroll
            for (int r = 0; r < 4; ++r) w_c[r] = w_n[r];
        }
    }

    // ---- reduce: sum over lg groups within wave, then across waves
    float* redw = reinterpret_cast<float*>(&e_lds[wv][0]);
    __syncthreads();   // ensure all E reads done before reuse as reduce buffer
#pragma unroll
    for (int t = 0; t < 8; ++t) {
        float v = aggp[t];
        v += __shfl_xor(v, 16);
        v += __shfl_xor(v, 32);
        if (lane < 16) redw[16 * t + lane] = v;
    }
    __syncthreads();
    if (tid < 128) {
        const float* r0 = reinterpret_cast<const float*>(&e_lds[0][0]);
        const float* r1 = reinterpret_cast<const float*>(&e_lds[1][0]);
        const float* r2 = reinterpret_cast<const float*>(&e_lds[2][0]);
        const float* r3 = reinterpret_cast<const float*>(&e_lds[3][0]);
        agg[(size_t)j * 128 + tid] = (r0[tid] + r1[tid] + r2[tid] + r3[tid]) * s_invdeg;
    }
}

// ---------------------------------------------------------------- update (+ next-round sp, or final out)
template <int LAST>
__global__ __launch_bounds__(256) void k_upd(
                      const float* __restrict__ h_in, const float* __restrict__ agg,
                      const float* __restrict__ Wu, const float* __restrict__ bu,
                      const float* __restrict__ Wa, const float* __restrict__ ba,
                      float* __restrict__ h_out, float* __restrict__ sp,
                      float* __restrict__ out) {
    __shared__ float buf[2][256];
    __shared__ float hn[2][128];
    const int tid = threadIdx.x;
    const int row = tid >> 7, t = tid & 127;
    const int i = blockIdx.x * 2 + row;
    buf[row][t] = h_in[i * 128 + t];
    buf[row][128 + t] = agg[i * 128 + t];
    __syncthreads();
    float acc = bu[t];
#pragma unroll 8
    for (int f = 0; f < 256; ++f) acc += buf[row][f] * Wu[f * 128 + t];
    acc = fmaxf(acc, 0.f);
    if (LAST) {
        out[i * 128 + t] = acc;
    } else {
        h_out[i * 128 + t] = acc;
        hn[row][t] = acc;
        __syncthreads();
        float spv = ba[t];
#pragma unroll 8
        for (int f = 0; f < 128; ++f) spv += hn[row][f] * Wa[f * 128 + t];
        sp[i * 128 + t] = spv;
    }
}

// ---------------------------------------------------------------- graph embedding (reads h from out)
__global__ __launch_bounds__(64) void k_gemb(const float* __restrict__ out_h, float* __restrict__ out) {
    int c = blockIdx.x, l = threadIdx.x;
    float acc = 0.f;
    for (int i = l; i < NN; i += 64) acc += out_h[(size_t)i * 128 + c];
#pragma unroll
    for (int off = 32; off; off >>= 1) acc += __shfl_down(acc, off);
    if (l == 0) out[NN * 128 + c] = acc * (1.0f / 768.0f);
}

extern "C" void kernel_launch(void* const* d_in, const int* in_sizes, int n_in,
                              void* d_out, int out_size, void* d_ws, size_t ws_size,
                              hipStream_t stream) {
    const float* nf  = (const float*)d_in[0];
    const float* ef  = (const float*)d_in[1];
    const float* adj = (const float*)d_in[2];
    const float* Wn  = (const float*)d_in[3];
    const float* bn  = (const float*)d_in[4];
    const float* We  = (const float*)d_in[5];
    const float* be  = (const float*)d_in[6];
    const float* Wa  = (const float*)d_in[7];
    const float* ba  = (const float*)d_in[8];
    const float* Wu  = (const float*)d_in[9];
    const float* bu  = (const float*)d_in[10];
    float* out = (float*)d_out;

    // workspace carve-up (floats): h | agg | sp | adjT | WeT(bf16) | Wa2T(bf16)
    float* h_buf = (float*)d_ws;
    float* agg   = h_buf + NN * 128;
    float* sp    = agg + NN * 128;
    float* adjT  = sp + NN * 128;
    unsigned short* WeT  = (unsigned short*)(adjT + NN * NN);
    unsigned short* Wa2T = WeT + 128 * 32;

    k_prep<<<1040, 256, 0, stream>>>(adj, adjT, We, Wa, WeT, Wa2T, nf, Wn, bn, ba, h_buf, sp);

    k_big<<<NN, 256, 0, stream>>>(ef, adjT, sp, WeT, Wa2T, be, agg);
    k_upd<0><<<NN / 2, 256, 0, stream>>>(h_buf, agg, Wu, bu, Wa, ba, h_buf, sp, out);
    k_big<<<NN, 256, 0, stream>>>(ef, adjT, sp, WeT, Wa2T, be, agg);
    k_upd<1><<<NN / 2, 256, 0, stream>>>(h_buf, agg, Wu, bu, Wa, ba, h_buf, sp, out);

    k_gemb<<<128, 64, 0, stream>>>(out, out);
}

// Round 8
// 143.552 us; speedup vs baseline: 2.5802x; 1.1430x over previous
//
#include <hip/hip_runtime.h>
#include <hip/hip_bf16.h>

// GraphSAGE fused kernels for MI355X (gfx950).
// N=768, NODE_IN=64, EDGE_IN=32, H=128, ROUNDS=2.
//
// Round 8: R5 structure (best: 148.6us; plain __launch_bounds__(256) is the
// only spill-free config) with organic register shaves to cross the
// 3-waves/SIMD boundary (VGPR<=170): bereg->be_lds (-8), sentinel sp row
// 768 = -1e30 replaces the w[] validity weights (-2 regs, -32 vmul/chunk;
// adj is binary so valid weight is always 1, relu kills sentinel rows).
// No sp prefetch (R7: +10us regression). LDS 51.2KB -> 3 blocks/CU.

typedef __bf16 bf16x8 __attribute__((ext_vector_type(8)));
typedef float f32x4 __attribute__((ext_vector_type(4)));

#define NN 768

static __device__ __forceinline__ unsigned short to_bf16u(float x) {
    return __builtin_bit_cast(unsigned short, (__bf16)x);
}

// ---------------------------------------------------------------- fused prep
// blocks 0..575   : adj transpose (32x32 tiles)
// blocks 576..655 : weight transposes We->WeT, Wa[H:]->Wa2T (bf16 k-minor)
// blocks 656..1039: h0 = relu(nf@Wn+bn) and sp = h0@Wa[:H]+ba (plain layout)
// block  1040     : sp sentinel row 768 = -1e30 (padded-slot C-init)
__global__ __launch_bounds__(256) void k_prep(
                       const float* __restrict__ adj, float* __restrict__ adjT,
                       const float* __restrict__ We, const float* __restrict__ Wa,
                       unsigned short* __restrict__ WeT, unsigned short* __restrict__ Wa2T,
                       const float* __restrict__ nf, const float* __restrict__ Wn,
                       const float* __restrict__ bn, const float* __restrict__ ba,
                       float* __restrict__ h, float* __restrict__ sp) {
    const int b = blockIdx.x, tid = threadIdx.x;
    if (b < 576) {
        __shared__ float tile[32][33];
        int bx = b % 24, by = b / 24;
        int tx = tid & 31, ty = tid >> 5;  // 32 x 8
#pragma unroll
        for (int yy = 0; yy < 32; yy += 8)
            tile[ty + yy][tx] = adj[(size_t)(by * 32 + ty + yy) * NN + bx * 32 + tx];
        __syncthreads();
#pragma unroll
        for (int yy = 0; yy < 32; yy += 8)
            adjT[(size_t)(bx * 32 + ty + yy) * NN + by * 32 + tx] = tile[tx][ty + yy];
    } else if (b < 656) {
        int g = (b - 576) * 256 + tid;
        if (g < 128 * 32) {
            int c = g >> 5, f = g & 31;
            WeT[g] = to_bf16u(We[f * 128 + c]);
        } else {
            int g2 = g - 128 * 32;
            int c = g2 >> 7, k = g2 & 127;
            Wa2T[g2] = to_bf16u(Wa[(128 + k) * 128 + c]);
        }
    } else if (b < 1040) {
        __shared__ float nf_l[2][64];
        __shared__ float h_l[2][128];
        int row = tid >> 7, t = tid & 127;
        int i = (b - 656) * 2 + row;
        if (t < 64) nf_l[row][t] = nf[i * 64 + t];
        __syncthreads();
        float acc = bn[t];
#pragma unroll 8
        for (int f = 0; f < 64; ++f) acc += nf_l[row][f] * Wn[f * 128 + t];
        acc = fmaxf(acc, 0.f);
        h[i * 128 + t] = acc;
        h_l[row][t] = acc;
        __syncthreads();
        float spv = ba[t];
#pragma unroll 8
        for (int f = 0; f < 128; ++f) spv += h_l[row][f] * Wa[f * 128 + t];
        sp[i * 128 + t] = spv;
    } else {
        if (tid < 128) sp[(size_t)NN * 128 + tid] = -1e30f;
    }
}

// ---------------------------------------------------------------- the big fused kernel
// Block = receiver j, 4 waves. Wave-0 compacts senders with adj[i,j]=1 into
// idx_lds; each wave then owns 16-row gathered chunks end-to-end.
__global__ __launch_bounds__(256) void k_big(
    const float* __restrict__ ef, const float* __restrict__ adjT,
    const float* __restrict__ sp, const unsigned short* __restrict__ WeT,
    const unsigned short* __restrict__ Wa2T, const float* __restrict__ be,
    float* __restrict__ agg) {
    __shared__ unsigned short wa2_lds[128 * 128];               // 32KB, XOR-swizzled
    __shared__ __align__(16) unsigned short e_lds[4][16 * 128]; // 4KB per wave
    __shared__ unsigned short idx_lds[NN];                      // compacted senders
    __shared__ float be_lds[128];
    __shared__ int s_cnt;
    __shared__ float s_invdeg;

    const int tid  = threadIdx.x;
    const int j    = blockIdx.x;
    const int lane = tid & 63;
    const int wv   = tid >> 6;
    const int lg   = lane >> 4;
    const int lr   = lane & 15;

    // ---- stage Wa2T -> swizzled LDS
    {
        const int col = tid >> 1;
        const int kb  = (tid & 1) * 64;
#pragma unroll
        for (int m = 0; m < 8; ++m) {
            bf16x8 v = *reinterpret_cast<const bf16x8*>(Wa2T + col * 128 + kb + 8 * m);
            int idx = (col * 128 + kb + 8 * m) ^ ((col & 7) << 3);
            *reinterpret_cast<bf16x8*>(&wa2_lds[idx]) = v;
        }
    }
    if (tid < 128) be_lds[tid] = be[tid];
    // ---- GEMM1 B-frags (We) in regs
    bf16x8 bwe[8];
#pragma unroll
    for (int t = 0; t < 8; ++t) {
        int col = 16 * t + lr;
        bwe[t] = *reinterpret_cast<const bf16x8*>(WeT + col * 32 + 8 * lg);
    }
    // ---- wave 0: ballot-compaction of adj column j
    if (wv == 0) {
        int cnt = 0;
#pragma unroll
        for (int b = 0; b < 12; ++b) {
            float v = adjT[(size_t)j * NN + b * 64 + lane];
            unsigned long long m = __ballot(v != 0.0f);
            if (v != 0.0f) {
                int pos = cnt + __popcll(m & ((1ULL << lane) - 1ULL));
                idx_lds[pos] = (unsigned short)(b * 64 + lane);
            }
            cnt += (int)__popcll(m);
        }
        if (lane == 0) {
            s_cnt = cnt;
            s_invdeg = 1.0f / fmaxf((float)cnt, 1.0f);
        }
    }
    __syncthreads();

    const int cnt = s_cnt;
    const int K = (cnt + 63) >> 6;   // super-chunks of 64 slots (16 per wave)

    float aggp[8] = {0.f, 0.f, 0.f, 0.f, 0.f, 0.f, 0.f, 0.f};

    // prefetch chunk 0 row for this lane (slot = 16wv + lr)
    float4 a0, a1;
    if (K > 0) {
        int s0 = 16 * wv + lr;
        int r0 = (s0 < cnt) ? (int)idx_lds[s0] : 0;
        const float* p = ef + ((size_t)r0 * NN + j) * 32 + 8 * lg;
        a0 = *reinterpret_cast<const float4*>(p);
        a1 = *reinterpret_cast<const float4*>(p + 4);
    }

    for (int n = 0; n < K; ++n) {
        const int sb = 64 * n + 16 * wv;    // this wave's slot base

        bf16x8 a;
        a[0] = (__bf16)a0.x; a[1] = (__bf16)a0.y; a[2] = (__bf16)a0.z; a[3] = (__bf16)a0.w;
        a[4] = (__bf16)a1.x; a[5] = (__bf16)a1.y; a[6] = (__bf16)a1.z; a[7] = (__bf16)a1.w;

        // prefetch next chunk's ef row
        float4 nx0, nx1;
        if (n + 1 < K) {
            int sn = sb + 64 + lr;
            int rn = (sn < cnt) ? (int)idx_lds[sn] : 0;
            const float* p = ef + ((size_t)rn * NN + j) * 32 + 8 * lg;
            nx0 = *reinterpret_cast<const float4*>(p);
            nx1 = *reinterpret_cast<const float4*>(p + 4);
        }

        // ---- GEMM1: E(16x128) = relu(EF @ We + be), write swizzled E
#pragma unroll
        for (int t = 0; t < 8; ++t) {
            float bb = be_lds[16 * t + lr];
            f32x4 c;
            c[0] = bb; c[1] = bb; c[2] = bb; c[3] = bb;
            f32x4 C1 = __builtin_amdgcn_mfma_f32_16x16x32_bf16(a, bwe[t], c, 0, 0, 0);
#pragma unroll
            for (int r = 0; r < 4; ++r) {
                int row = 4 * lg + r, col = 16 * t + lr;
                int idx = (row * 128 + col) ^ ((row & 7) << 3);
                e_lds[wv][idx] = to_bf16u(fmaxf(C1[r], 0.f));
            }
        }
        // ---- GEMM2 A-frags from private E (wave-synchronous round trip)
        bf16x8 ae[4];
#pragma unroll
        for (int s = 0; s < 4; ++s) {
            int idx = (lr * 128 + 32 * s + 8 * lg) ^ ((lr & 7) << 3);
            ae[s] = *reinterpret_cast<const bf16x8*>(&e_lds[wv][idx]);
        }
        // C/D row slots: invalid slots -> sentinel row 768 (sp = -1e30, relu kills)
        int srow[4];
#pragma unroll
        for (int r = 0; r < 4; ++r) {
            int s = sb + 4 * lg + r;
            srow[r] = (s < cnt) ? (int)idx_lds[s] : NN;
        }
        // ---- GEMM2: P = E @ Wa2 + sp(gathered), relu, accumulate
#pragma unroll
        for (int t = 0; t < 8; ++t) {
            const int col = 16 * t + lr;
            f32x4 acc;
#pragma unroll
            for (int r = 0; r < 4; ++r)
                acc[r] = sp[(size_t)srow[r] * 128 + col];
#pragma unroll
            for (int s = 0; s < 4; ++s) {
                int widx = (col * 128 + 32 * s + 8 * lg) ^ ((col & 7) << 3);
                bf16x8 bw = *reinterpret_cast<const bf16x8*>(&wa2_lds[widx]);
                acc = __builtin_amdgcn_mfma_f32_16x16x32_bf16(ae[s], bw, acc, 0, 0, 0);
            }
#pragma unroll
            for (int r = 0; r < 4; ++r)
                aggp[t] += fmaxf(acc[r], 0.f);
        }

        if (n + 1 < K) { a0 = nx0; a1 = nx1; }
    }

    // ---- reduce: sum over lg groups within wave, then across waves
    float* redw = reinterpret_cast<float*>(&e_lds[wv][0]);
    __syncthreads();   // ensure all E reads done before reuse as reduce buffer
#pragma unroll
    for (int t = 0; t < 8; ++t) {
        float v = aggp[t];
        v += __shfl_xor(v, 16);
        v += __shfl_xor(v, 32);
        if (lane < 16) redw[16 * t + lane] = v;
    }
    __syncthreads();
    if (tid < 128) {
        const float* r0 = reinterpret_cast<const float*>(&e_lds[0][0]);
        const float* r1 = reinterpret_cast<const float*>(&e_lds[1][0]);
        const float* r2 = reinterpret_cast<const float*>(&e_lds[2][0]);
        const float* r3 = reinterpret_cast<const float*>(&e_lds[3][0]);
        agg[(size_t)j * 128 + tid] = (r0[tid] + r1[tid] + r2[tid] + r3[tid]) * s_invdeg;
    }
}

// ---------------------------------------------------------------- update (+ next-round sp, or final out)
template <int LAST>
__global__ __launch_bounds__(256) void k_upd(
                      const float* __restrict__ h_in, const float* __restrict__ agg,
                      const float* __restrict__ Wu, const float* __restrict__ bu,
                      const float* __restrict__ Wa, const float* __restrict__ ba,
                      float* __restrict__ h_out, float* __restrict__ sp,
                      float* __restrict__ out) {
    __shared__ float buf[2][256];
    __shared__ float hn[2][128];
    const int tid = threadIdx.x;
    const int row = tid >> 7, t = tid & 127;
    const int i = blockIdx.x * 2 + row;
    buf[row][t] = h_in[i * 128 + t];
    buf[row][128 + t] = agg[i * 128 + t];
    __syncthreads();
    float acc = bu[t];
#pragma unroll 8
    for (int f = 0; f < 256; ++f) acc += buf[row][f] * Wu[f * 128 + t];
    acc = fmaxf(acc, 0.f);
    if (LAST) {
        out[i * 128 + t] = acc;
    } else {
        h_out[i * 128 + t] = acc;
        hn[row][t] = acc;
        __syncthreads();
        float spv = ba[t];
#pragma unroll 8
        for (int f = 0; f < 128; ++f) spv += hn[row][f] * Wa[f * 128 + t];
        sp[i * 128 + t] = spv;
    }
}

// ---------------------------------------------------------------- graph embedding (reads h from out)
__global__ __launch_bounds__(64) void k_gemb(const float* __restrict__ out_h, float* __restrict__ out) {
    int c = blockIdx.x, l = threadIdx.x;
    float acc = 0.f;
    for (int i = l; i < NN; i += 64) acc += out_h[(size_t)i * 128 + c];
#pragma unroll
    for (int off = 32; off; off >>= 1) acc += __shfl_down(acc, off);
    if (l == 0) out[NN * 128 + c] = acc * (1.0f / 768.0f);
}

extern "C" void kernel_launch(void* const* d_in, const int* in_sizes, int n_in,
                              void* d_out, int out_size, void* d_ws, size_t ws_size,
                              hipStream_t stream) {
    const float* nf  = (const float*)d_in[0];
    const float* ef  = (const float*)d_in[1];
    const float* adj = (const float*)d_in[2];
    const float* Wn  = (const float*)d_in[3];
    const float* bn  = (const float*)d_in[4];
    const float* We  = (const float*)d_in[5];
    const float* be  = (const float*)d_in[6];
    const float* Wa  = (const float*)d_in[7];
    const float* ba  = (const float*)d_in[8];
    const float* Wu  = (const float*)d_in[9];
    const float* bu  = (const float*)d_in[10];
    float* out = (float*)d_out;

    // workspace carve-up (floats): h | agg | sp(+sentinel row) | adjT | WeT | Wa2T
    float* h_buf = (float*)d_ws;
    float* agg   = h_buf + NN * 128;
    float* sp    = agg + NN * 128;
    float* adjT  = sp + (NN + 1) * 128;
    unsigned short* WeT  = (unsigned short*)(adjT + NN * NN);
    unsigned short* Wa2T = WeT + 128 * 32;

    k_prep<<<1041, 256, 0, stream>>>(adj, adjT, We, Wa, WeT, Wa2T, nf, Wn, bn, ba, h_buf, sp);

    k_big<<<NN, 256, 0, stream>>>(ef, adjT, sp, WeT, Wa2T, be, agg);
    k_upd<0><<<NN / 2, 256, 0, stream>>>(h_buf, agg, Wu, bu, Wa, ba, h_buf, sp, out);
    k_big<<<NN, 256, 0, stream>>>(ef, adjT, sp, WeT, Wa2T, be, agg);
    k_upd<1><<<NN / 2, 256, 0, stream>>>(h_buf, agg, Wu, bu, Wa, ba, h_buf, sp, out);

    k_gemb<<<128, 64, 0, stream>>>(out, out);
}